// Round 2
// baseline (1176.062 us; speedup 1.0000x reference)
//
#include <hip/hip_runtime.h>

// Correlation layer v6.
// v4 (308us): latency-bound, VALUBusy 13%, HBM 14% -> staging latency exposed
//   between barriers, nothing in flight across compute.
// v5 (FAILED): global_load_lds staging under exec mask -> LDS dest base is
//   wave-uniform (readfirstlane over ACTIVE lanes); edge tiles with masked
//   OOB lanes got a shifted base -> corrupted borders (absmax 6.9).
// v6: same async double-buffered pipeline, but reg-staged (global->VGPR early,
//   ds_write late). DS writes are genuinely per-lane + exec-masked = safe.
//   Issue order per chunk: x1 loads (oldest) -> stage loads (youngest) ->
//   compute (per-cc waits retire x1 only, stage stays in flight) -> ds_write
//   (drains stage) -> one barrier. OOB slots pre-zeroed once, never rewritten
//   (OOB lanes read a clamped addr, stride 0, and skip the ds_write).
//   XCD swizzle: bid&7 = batch image per XCD -> halo re-reads are L2 hits.

#define B_  8
#define C_  128
#define H_  128
#define W_  192
#define HW_ (H_*W_)
#define HALO 4
#define WT  32              // tile width (px)
#define HT  8               // tile height (px)
#define CC  4               // channels per chunk
#define NCHUNK (C_/CC)      // 32
#define X2C 40              // tile row width incl halo (floats)
#define X2SZ 640            // floats per channel (16 rows * 40)
#define BUFSZ (CC*X2SZ)     // 2560 floats per buffer
#define NTHREADS 576        // 8 x 8 x 9 = 9 waves

__global__ __launch_bounds__(NTHREADS, 5) void corr_kernel(
    const float* __restrict__ x1, const float* __restrict__ x2,
    float* __restrict__ out)
{
    __shared__ float x2s[2][BUFSZ];   // 2*2560*4 = 20480 B

    const int tx = threadIdx.x;           // 0..7 : 4-px column group
    const int ty = threadIdx.y;           // 0..7 : row within tile
    const int iz = threadIdx.z;           // 0..8 : displacement row (one wave)
    const int tid = tx + 8*ty + 64*iz;    // 0..575

    // XCD swizzle: consecutive blockIdx round-robin over 8 XCDs; bid&7 pins
    // one batch image per XCD, tiles row-major within the image.
    const int bid   = blockIdx.x;
    const int b     = bid & 7;
    const int t     = bid >> 3;           // 0..95
    const int w0t = (t % 6) * WT;
    const int h0t = (t / 6) * HT;

    const float* x1b = x1 + (size_t)b * C_ * HW_;
    const float* x2b = x2 + (size_t)b * C_ * HW_;

    // ---- staging float4 slots (chunk-invariant) ----
    // slot e0 = tid (all threads); slot e1 = tid+576 (iz==0 wave only)
    const int e0  = tid;
    const int ch0 = e0 / 160;                  // 160 float4 per channel
    const int r0  = (e0 - 160*ch0) / 10;       // 10 float4 per row
    const int cq0 = e0 - 160*ch0 - 10*r0;
    const int gh0 = h0t - HALO + r0;
    const int gw0 = w0t - HALO + 4*cq0;        // aligned; f4 fully in or out
    const bool inb0 = ((unsigned)gh0 < (unsigned)H_) && ((unsigned)gw0 < (unsigned)W_);
    const int  l0   = 4 * e0;                  // linear float offset in buffer
    const float* ps0 = x2b + (inb0 ? ((long)ch0 * HW_ + (long)gh0 * W_ + gw0) : 0);
    const long  st0 = inb0 ? (long)CC * HW_ : 0;   // OOB: reload same addr (L1 hit)

    const int e1  = tid + NTHREADS;            // meaningful only for iz==0
    const int ch1 = e1 / 160;
    const int r1  = (e1 - 160*ch1) / 10;
    const int cq1 = e1 - 160*ch1 - 10*r1;
    const int gh1 = h0t - HALO + r1;
    const int gw1 = w0t - HALO + 4*cq1;
    const bool inb1 = ((unsigned)gh1 < (unsigned)H_) && ((unsigned)gw1 < (unsigned)W_);
    const int  l1   = 4 * e1;
    const float* ps1 = x2b + (inb1 ? ((long)ch1 * HW_ + (long)gh1 * W_ + gw1) : 0);
    const long  st1 = inb1 ? (long)CC * HW_ : 0;

    // OOB slots: zero once in BOTH buffers; never rewritten afterwards.
    const float4 fz = make_float4(0.f, 0.f, 0.f, 0.f);
    if (!inb0) {
        *(float4*)&x2s[0][l0] = fz;
        *(float4*)&x2s[1][l0] = fz;
    }
    if (iz == 0 && !inb1) {
        *(float4*)&x2s[0][l1] = fz;
        *(float4*)&x2s[1][l1] = fz;
    }

    // prologue: stage chunk 0 into buffer 0
    {
        const float4 t0 = *(const float4*)ps0;
        if (inb0) *(float4*)&x2s[0][l0] = t0;
        if (iz == 0) {
            const float4 t1 = *(const float4*)ps1;
            if (inb1) *(float4*)&x2s[0][l1] = t1;
        }
    }
    __syncthreads();

    const float* x1t = x1b + (h0t + ty) * W_ + w0t + 4 * tx;
    const int woff = (ty + iz) * X2C + 4 * tx;

    float acc[9][4];
    #pragma unroll
    for (int j = 0; j < 9; j++)
        #pragma unroll
        for (int p = 0; p < 4; p++) acc[j][p] = 0.f;

    #pragma unroll 2
    for (int k = 0; k < NCHUNK; ++k) {
        const int cb = k * CC;
        const bool more = (k + 1 < NCHUNK);

        // x1 loads FIRST: oldest vmcnt slots, so per-cc FMA waits retire these
        // without draining the (younger) stage loads.
        float4 a[CC];
        #pragma unroll
        for (int cc = 0; cc < CC; ++cc)
            a[cc] = *(const float4*)(x1t + (size_t)(cb + cc) * HW_);

        // stage loads for chunk k+1 -> VGPRs; in flight across the compute.
        float4 t0, t1;
        if (more) {
            t0 = *(const float4*)(ps0 + (long)(k + 1) * st0);
            if (iz == 0) t1 = *(const float4*)(ps1 + (long)(k + 1) * st1);
        }

        // compute chunk k from current buffer
        const float* buf = &x2s[k & 1][0];
        #pragma unroll
        for (int cc = 0; cc < CC; ++cc) {
            const float* row = buf + cc * X2SZ + woff;
            const float4 w0 = *(const float4*)(row);
            const float4 w1 = *(const float4*)(row + 4);
            const float4 w2 = *(const float4*)(row + 8);
            const float av[4] = {a[cc].x, a[cc].y, a[cc].z, a[cc].w};
            const float rr[12] = {w0.x, w0.y, w0.z, w0.w,
                                  w1.x, w1.y, w1.z, w1.w,
                                  w2.x, w2.y, w2.z, w2.w};
            #pragma unroll
            for (int j = 0; j < 9; j++)
                #pragma unroll
                for (int p = 0; p < 4; p++)
                    acc[j][p] = fmaf(av[p], rr[j + p], acc[j][p]);
        }

        // write chunk k+1 into the other buffer (per-lane DS, exec-masked: safe)
        if (more) {
            float* dst = &x2s[(k & 1) ^ 1][0];
            if (inb0) *(float4*)(dst + l0) = t0;
            if (iz == 0 && inb1) *(float4*)(dst + l1) = t1;
        }

        __syncthreads();   // stage visible to all; this chunk's reads done
    }

    // epilogue: scale + write up to 9 float4 channels
    const float scale = 0.08838834764831845f;   // 1/sqrt(128)
    const int h  = h0t + ty;
    const int w0 = w0t + tx*4;
    float* outb = out + (size_t)b * 80 * HW_ + (size_t)h * W_ + w0;
    #pragma unroll
    for (int j = 0; j < 9; j++) {
        const int gi = iz * 9 + j;          // 0..80, wave-uniform
        if (gi == 40) continue;             // skip (0,0) displacement
        const int ch = gi - (gi > 40 ? 1 : 0);
        float4 v;
        v.x = acc[j][0] * scale;
        v.y = acc[j][1] * scale;
        v.z = acc[j][2] * scale;
        v.w = acc[j][3] * scale;
        *(float4*)(outb + (size_t)ch * HW_) = v;
    }
}

extern "C" void kernel_launch(void* const* d_in, const int* in_sizes, int n_in,
                              void* d_out, int out_size, void* d_ws, size_t ws_size,
                              hipStream_t stream) {
    const float* x1 = (const float*)d_in[0];
    const float* x2 = (const float*)d_in[1];
    float* out = (float*)d_out;

    dim3 block(8, 8, 9);                       // 576 threads = 9 waves
    dim3 grid(768, 1, 1);                      // 6*16*8, linearized for swizzle
    corr_kernel<<<grid, block, 0, stream>>>(x1, x2, out);
}

// Round 3
// 397.564 us; speedup vs baseline: 2.9582x; 2.9582x over previous
//
#include <hip/hip_runtime.h>

// Correlation layer v7.
// v4 (308us): latency-bound, VALUBusy 13%, HBM 14% -> synchronous staging
//   between two barriers, nothing in flight across compute.
// v5 (FAILED): global_load_lds under exec mask -> wave-uniform LDS base over
//   ACTIVE lanes shifted edge tiles. Don't mask global_load_lds.
// v6 (1037us): correct reg-staged pipeline, but __launch_bounds__(576,5)
//   strangled the allocator -> 48 VGPR, acc tile SPILLED to scratch
//   (WRITE_SIZE 61MB->2.5GB, FETCH 270MB->1.5GB). Pipeline never got a fair
//   test.
// v7 = v6 with __launch_bounds__(576,2) (v4's working bound, ~256-reg cap):
//   reg-staged double-buffered pipeline, one barrier per chunk, x1 loads
//   issued before stage loads (in-order vmcnt retirement -> per-cc FMA waits
//   don't drain the stage queue), XCD swizzle (bid&7 = one image per XCD),
//   chunk-invariant pre-zeroed OOB slots.

#define B_  8
#define C_  128
#define H_  128
#define W_  192
#define HW_ (H_*W_)
#define HALO 4
#define WT  32              // tile width (px)
#define HT  8               // tile height (px)
#define CC  4               // channels per chunk
#define NCHUNK (C_/CC)      // 32
#define X2C 40              // tile row width incl halo (floats)
#define X2SZ 640            // floats per channel (16 rows * 40)
#define BUFSZ (CC*X2SZ)     // 2560 floats per buffer
#define NTHREADS 576        // 8 x 8 x 9 = 9 waves

__global__ __launch_bounds__(NTHREADS, 2) void corr_kernel(
    const float* __restrict__ x1, const float* __restrict__ x2,
    float* __restrict__ out)
{
    __shared__ float x2s[2][BUFSZ];   // 2*2560*4 = 20480 B

    const int tx = threadIdx.x;           // 0..7 : 4-px column group
    const int ty = threadIdx.y;           // 0..7 : row within tile
    const int iz = threadIdx.z;           // 0..8 : displacement row (one wave)
    const int tid = tx + 8*ty + 64*iz;    // 0..575

    // XCD swizzle: consecutive blockIdx round-robin over 8 XCDs; bid&7 pins
    // one batch image per XCD, tiles row-major within the image.
    const int bid   = blockIdx.x;
    const int b     = bid & 7;
    const int t     = bid >> 3;           // 0..95
    const int w0t = (t % 6) * WT;
    const int h0t = (t / 6) * HT;

    const float* x1b = x1 + (size_t)b * C_ * HW_;
    const float* x2b = x2 + (size_t)b * C_ * HW_;

    // ---- staging float4 slots (chunk-invariant) ----
    // slot e0 = tid (all threads); slot e1 = tid+576 (iz==0 wave only)
    const int e0  = tid;
    const int ch0 = e0 / 160;                  // 160 float4 per channel
    const int r0  = (e0 - 160*ch0) / 10;       // 10 float4 per row
    const int cq0 = e0 - 160*ch0 - 10*r0;
    const int gh0 = h0t - HALO + r0;
    const int gw0 = w0t - HALO + 4*cq0;        // aligned; f4 fully in or out
    const bool inb0 = ((unsigned)gh0 < (unsigned)H_) && ((unsigned)gw0 < (unsigned)W_);
    const int  l0   = 4 * e0;                  // linear float offset in buffer
    const float* ps0 = x2b + (inb0 ? ((long)ch0 * HW_ + (long)gh0 * W_ + gw0) : 0);
    const long  st0 = inb0 ? (long)CC * HW_ : 0;   // OOB: reload same addr (L1 hit)

    const int e1  = tid + NTHREADS;            // meaningful only for iz==0
    const int ch1 = e1 / 160;
    const int r1  = (e1 - 160*ch1) / 10;
    const int cq1 = e1 - 160*ch1 - 10*r1;
    const int gh1 = h0t - HALO + r1;
    const int gw1 = w0t - HALO + 4*cq1;
    const bool inb1 = ((unsigned)gh1 < (unsigned)H_) && ((unsigned)gw1 < (unsigned)W_);
    const int  l1   = 4 * e1;
    const float* ps1 = x2b + (inb1 ? ((long)ch1 * HW_ + (long)gh1 * W_ + gw1) : 0);
    const long  st1 = inb1 ? (long)CC * HW_ : 0;

    // OOB slots: zero once in BOTH buffers; never rewritten afterwards.
    const float4 fz = make_float4(0.f, 0.f, 0.f, 0.f);
    if (!inb0) {
        *(float4*)&x2s[0][l0] = fz;
        *(float4*)&x2s[1][l0] = fz;
    }
    if (iz == 0 && !inb1) {
        *(float4*)&x2s[0][l1] = fz;
        *(float4*)&x2s[1][l1] = fz;
    }

    // prologue: stage chunk 0 into buffer 0
    {
        const float4 t0 = *(const float4*)ps0;
        if (inb0) *(float4*)&x2s[0][l0] = t0;
        if (iz == 0) {
            const float4 t1 = *(const float4*)ps1;
            if (inb1) *(float4*)&x2s[0][l1] = t1;
        }
    }
    __syncthreads();

    const float* x1t = x1b + (h0t + ty) * W_ + w0t + 4 * tx;
    const int woff = (ty + iz) * X2C + 4 * tx;

    float acc[9][4];
    #pragma unroll
    for (int j = 0; j < 9; j++)
        #pragma unroll
        for (int p = 0; p < 4; p++) acc[j][p] = 0.f;

    #pragma unroll 2
    for (int k = 0; k < NCHUNK; ++k) {
        const int cb = k * CC;
        const bool more = (k + 1 < NCHUNK);

        // x1 loads FIRST: oldest vmcnt slots, so per-cc FMA waits retire these
        // without draining the (younger) stage loads.
        float4 a[CC];
        #pragma unroll
        for (int cc = 0; cc < CC; ++cc)
            a[cc] = *(const float4*)(x1t + (size_t)(cb + cc) * HW_);

        // stage loads for chunk k+1 -> VGPRs; in flight across the compute.
        float4 t0, t1;
        if (more) {
            t0 = *(const float4*)(ps0 + (long)(k + 1) * st0);
            if (iz == 0) t1 = *(const float4*)(ps1 + (long)(k + 1) * st1);
        }

        // compute chunk k from current buffer
        const float* buf = &x2s[k & 1][0];
        #pragma unroll
        for (int cc = 0; cc < CC; ++cc) {
            const float* row = buf + cc * X2SZ + woff;
            const float4 w0 = *(const float4*)(row);
            const float4 w1 = *(const float4*)(row + 4);
            const float4 w2 = *(const float4*)(row + 8);
            const float av[4] = {a[cc].x, a[cc].y, a[cc].z, a[cc].w};
            const float rr[12] = {w0.x, w0.y, w0.z, w0.w,
                                  w1.x, w1.y, w1.z, w1.w,
                                  w2.x, w2.y, w2.z, w2.w};
            #pragma unroll
            for (int j = 0; j < 9; j++)
                #pragma unroll
                for (int p = 0; p < 4; p++)
                    acc[j][p] = fmaf(av[p], rr[j + p], acc[j][p]);
        }

        // write chunk k+1 into the other buffer (per-lane DS, exec-masked: safe)
        if (more) {
            float* dst = &x2s[(k & 1) ^ 1][0];
            if (inb0) *(float4*)(dst + l0) = t0;
            if (iz == 0 && inb1) *(float4*)(dst + l1) = t1;
        }

        __syncthreads();   // stage visible to all; this chunk's reads done
    }

    // epilogue: scale + write up to 9 float4 channels
    const float scale = 0.08838834764831845f;   // 1/sqrt(128)
    const int h  = h0t + ty;
    const int w0 = w0t + tx*4;
    float* outb = out + (size_t)b * 80 * HW_ + (size_t)h * W_ + w0;
    #pragma unroll
    for (int j = 0; j < 9; j++) {
        const int gi = iz * 9 + j;          // 0..80, wave-uniform
        if (gi == 40) continue;             // skip (0,0) displacement
        const int ch = gi - (gi > 40 ? 1 : 0);
        float4 v;
        v.x = acc[j][0] * scale;
        v.y = acc[j][1] * scale;
        v.z = acc[j][2] * scale;
        v.w = acc[j][3] * scale;
        *(float4*)(outb + (size_t)ch * HW_) = v;
    }
}

extern "C" void kernel_launch(void* const* d_in, const int* in_sizes, int n_in,
                              void* d_out, int out_size, void* d_ws, size_t ws_size,
                              hipStream_t stream) {
    const float* x1 = (const float*)d_in[0];
    const float* x2 = (const float*)d_in[1];
    float* out = (float*)d_out;

    dim3 block(8, 8, 9);                       // 576 threads = 9 waves
    dim3 grid(768, 1, 1);                      // 6*16*8, linearized for swizzle
    corr_kernel<<<grid, block, 0, stream>>>(x1, x2, out);
}